// Round 6
// baseline (377.074 us; speedup 1.0000x reference)
//
#include <hip/hip_runtime.h>

// GatedMoE on MI355X (gfx950), fp16 MFMA path, round 10.
// vs r9: (1) cvt-W2 blocks interleaved with gemm1 blocks (groups of 8+8)
// instead of appended -> tail overlap; (2) cvt rewritten wave-private
// (64x64 / 64x32 tiles per wave, no __syncthreads, conflict-free lane=col
// reads, aligned pad-68/36); (3) gemm2 atomics removed: plain fp32 stores
// to ybuf (aliases dead w1t region) + inv map from scan + gather kernel
// out[tok] = sum w_k*ybuf[slot_k]; memset dispatch deleted.

typedef _Float16 half8 __attribute__((ext_vector_type(8)));
typedef _Float16 half4t __attribute__((ext_vector_type(4)));
typedef float f4 __attribute__((ext_vector_type(4)));

#define N_TOK 4096
#define DDIM  768
#define HDIM  2048
#define NEXP  8
#define CAP   614   // int(1.2 * 4096 / 8)
#define CAPP  640

// ---- workspace layout (bytes) ----
#define XH_OFF    0L           // (4097*768) fp16
#define W1T_OFF   6292992L     // [8][4096][768] fp16 (dead after gemm1)
#define YB_OFF    6292992L     // [16][640][768] fp32 ybuf (gemm2->gather), aliases w1t
#define W2T_OFF   56624640L    // [8][768][2048] fp16
#define ACT_OFF   81790464L    // [16][640][2048] fp16
#define EIDX_OFF  123733504L   // [4096][2] int
#define WTS_OFF   123766272L   // [4096][2] float
#define TOKL_OFF  123799040L   // [16][640] int
#define CNT_OFF   123840000L   // [16] int
#define INV_OFF   123840256L   // [4096][2] int (tok,k) -> z*CAPP+slot | -1

__device__ __forceinline__ void gld16(const void* g, void* l) {
  __builtin_amdgcn_global_load_lds(
      (const __attribute__((address_space(1))) unsigned int*)g,
      (__attribute__((address_space(3))) unsigned int*)l, 16, 0, 0);
}

// -------------------- wave-private transpose+convert --------------------
// 64x64 fp32 tile -> fp16 transposed. No block barrier: wave owns its tile.
// Pad 68 (even) keeps f4 LDS writes 16B-aligned; reads are lane=col (conflict-free).
__device__ __forceinline__ void cvt_wave64(const float* __restrict__ src,
                                           _Float16* __restrict__ dst,
                                           int R, int C, int e, int r0, int c0,
                                           float* __restrict__ wt, int lane) {
  long sb = (long)e * R * C;
  int lr = lane >> 4, l4 = (lane & 15) * 4;
#pragma unroll
  for (int s = 0; s < 16; s++) {
    int row = s * 4 + lr;
    f4 v = *(const f4*)(src + sb + (long)(r0 + row) * C + c0 + l4);
    *(f4*)(&wt[row * 68 + l4]) = v;
  }
  asm volatile("s_waitcnt lgkmcnt(0)" ::: "memory");   // own wave's LDS writes done
  int c = lane;
#pragma unroll
  for (int ch = 0; ch < 8; ch++) {
    half8 h;
#pragma unroll
    for (int j = 0; j < 8; j++) h[j] = (_Float16)wt[(ch * 8 + j) * 68 + c];
    *(half8*)(dst + sb + (long)(c0 + c) * R + r0 + ch * 8) = h;
  }
}

// 64x32 variant (fits in gemm1's LDS budget): 9216 B/wave.
__device__ __forceinline__ void cvt_wave32(const float* __restrict__ src,
                                           _Float16* __restrict__ dst,
                                           int R, int C, int e, int r0, int c0,
                                           float* __restrict__ wt, int lane) {
  long sb = (long)e * R * C;
  int r8 = lane >> 3, l4 = (lane & 7) * 4;
#pragma unroll
  for (int s = 0; s < 8; s++) {
    int row = s * 8 + r8;
    f4 v = *(const f4*)(src + sb + (long)(r0 + row) * C + c0 + l4);
    *(f4*)(&wt[row * 36 + l4]) = v;
  }
  asm volatile("s_waitcnt lgkmcnt(0)" ::: "memory");
  int c = lane & 31, h2 = lane >> 5;
#pragma unroll
  for (int ch = 0; ch < 4; ch++) {
    half8 h;
#pragma unroll
    for (int j = 0; j < 8; j++) h[j] = (_Float16)wt[(h2 * 32 + ch * 8 + j) * 36 + c];
    *(half8*)(dst + sb + (long)(c0 + c) * R + r0 + h2 * 32 + ch * 8) = h;
  }
}

// -------------------- prep1: router | cvt_tr(W1) --------------------
// blocks [0,1025): router + x->fp16; [1025,2561): W1 cvt (64x256/block, 4 waves)
__global__ __launch_bounds__(256) void prep1_kernel(const float* __restrict__ W1,
                                                    const float* __restrict__ x,
                                                    const float* __restrict__ Wg,
                                                    _Float16* __restrict__ w1t,
                                                    _Float16* __restrict__ xh,
                                                    int* __restrict__ eidx,
                                                    float* __restrict__ wts) {
  __shared__ float pls[4 * 64 * 68];   // 69.6 KB (4 wave tiles) / wgT (24 KB)
  int b = blockIdx.x;
  int t = threadIdx.x;
  int w = t >> 6, lane = t & 63;

  if (b >= 1025) {                     // ---- cvt W1: 768x4096 per expert
    int cb = b - 1025;                 // 0..1535
    int e = cb / 192, rem = cb % 192;  // 12 r-tiles x 16 c256-tiles
    int cx = rem % 12, cy = rem / 12;
    cvt_wave64(W1, w1t, 768, 4096, e, cx * 64, cy * 256 + w * 64, pls + w * (64 * 68), lane);
    return;
  }

  // ---- router
  for (int i = t; i < DDIM * NEXP; i += 256) pls[(i & 7) * DDIM + (i >> 3)] = Wg[i];
  __syncthreads();
  int tok = b * 4 + w;
  if (tok > N_TOK) return;
  if (tok == N_TOK) {                  // zero pad row
    half4t zz; zz[0] = zz[1] = zz[2] = zz[3] = (_Float16)0.f;
#pragma unroll
    for (int j = 0; j < 3; j++) *(half4t*)(xh + (long)N_TOK * DDIM + (lane + j * 64) * 4) = zz;
    return;
  }
  const float* xr = x + (long)tok * DDIM;
#pragma unroll
  for (int j = 0; j < 3; j++) {
    f4 v = *(const f4*)(xr + (lane + j * 64) * 4);
    half4t hv;
    hv[0] = (_Float16)v[0]; hv[1] = (_Float16)v[1];
    hv[2] = (_Float16)v[2]; hv[3] = (_Float16)v[3];
    *(half4t*)(xh + (long)tok * DDIM + (lane + j * 64) * 4) = hv;
  }
  float acc[8] = {0.f, 0.f, 0.f, 0.f, 0.f, 0.f, 0.f, 0.f};
#pragma unroll
  for (int i = 0; i < 12; i++) {
    float xv = xr[i * 64 + lane];
#pragma unroll
    for (int e2 = 0; e2 < 8; e2++) acc[e2] += xv * pls[e2 * DDIM + i * 64 + lane];
  }
#pragma unroll
  for (int e2 = 0; e2 < 8; e2++) {
    float v = acc[e2];
    v += __shfl_xor(v, 32); v += __shfl_xor(v, 16); v += __shfl_xor(v, 8);
    v += __shfl_xor(v, 4);  v += __shfl_xor(v, 2);  v += __shfl_xor(v, 1);
    acc[e2] = v;
  }
  if (lane == 0) {
    float m0 = -1e30f; int i0 = 0;
#pragma unroll
    for (int e2 = 0; e2 < 8; e2++) if (acc[e2] > m0) { m0 = acc[e2]; i0 = e2; }
    float m1 = -1e30f; int i1 = 0;
#pragma unroll
    for (int e2 = 0; e2 < 8; e2++) if (e2 != i0 && acc[e2] > m1) { m1 = acc[e2]; i1 = e2; }
    float tt = __expf(m1 - m0);
    float w0 = 1.f / (1.f + tt);
    eidx[tok * 2 + 0] = i0; eidx[tok * 2 + 1] = i1;
    wts[tok * 2 + 0] = w0;  wts[tok * 2 + 1] = 1.f - w0;
  }
}

// -------------------- capacity scan (+ inverse map) --------------------
__global__ __launch_bounds__(64) void scan_kernel(const int* __restrict__ eidx,
                                                  int* __restrict__ toklist,
                                                  int* __restrict__ counts,
                                                  int* __restrict__ inv) {
  int z = blockIdx.x;
  int k = z >> 3, e = z & 7;
  int lane = threadIdx.x;
  int mye[64];
#pragma unroll
  for (int c = 0; c < 64; c++) mye[c] = eidx[(c * 64 + lane) * 2 + k];
  int base = 0;
#pragma unroll 4
  for (int c = 0; c < 64; c++) {
    int n = c * 64 + lane;
    bool pred = (mye[c] == e);
    unsigned long long mask = __ballot(pred);
    if (pred) {
      int pos = base + __popcll(mask & ((1ull << lane) - 1ull));
      if (pos < CAP) {
        toklist[z * CAPP + pos] = n;
        inv[n * 2 + k] = z * CAPP + pos;
      } else {
        inv[n * 2 + k] = -1;              // capacity-dropped
      }
    }
    base += __popcll(mask);
  }
  if (lane == 0) counts[z] = (base < CAP) ? base : CAP;
}

// -------------------- GEMM1 + fused SwiGLU | interleaved cvt_tr(W2) --------------------
// 2816 blocks. For i<2560 in groups of 16: r<8 -> gemm1 block g*8+r (keeps
// e = r XCD alignment), r>=8 -> cvt-W2 block g*8+(r-8). i>=2560 -> cvt tail.
__global__ __launch_bounds__(256, 2) void gemm1_kernel(const _Float16* __restrict__ xh,
                                                       const _Float16* __restrict__ w1t,
                                                       const float* __restrict__ W2,
                                                       _Float16* __restrict__ w2t,
                                                       const int* __restrict__ toklist,
                                                       const int* __restrict__ counts,
                                                       _Float16* __restrict__ act) {
  __shared__ float smemf[12416];   // 49664 B: gemm1 As|Bs|toks, cvt: 4x9216 B

  int t = threadIdx.x;
  int i = blockIdx.x;
  int gi = -1, ci = -1;
  if (i < 2560) { int g = i >> 4, r = i & 15; if (r < 8) gi = g * 8 + r; else ci = g * 8 + (r - 8); }
  else ci = 1280 + (i - 2560);

  if (ci >= 0) {                     // ---- cvt W2: 2048x768 per expert
    int e = ci / 192, rem = ci % 192;  // 32 r-tiles x 6 c128-tiles
    int cx = rem % 32, cc = rem / 32;
    int w = t >> 6, lane = t & 63;
    cvt_wave32(W2, w2t, 2048, 768, e, cx * 64, cc * 128 + w * 32, smemf + w * 2304, lane);
    return;
  }

  _Float16* As = (_Float16*)smemf;             // 128*64
  _Float16* Bs = (_Float16*)(smemf + 4096);    // 256*64
  int* toks = (int*)(smemf + 12288);           // 128

  int xcd = gi & 7, j = gi >> 3;     // 1280 gemm1 blocks, 160/xcd
  int m = j % 5, ii = j / 5;
  int k = ii & 1, n = ii >> 1;
  int e = xcd, z = k * 8 + e;
  int count = counts[z];
  int m0 = m * 128;
  if (m0 >= count) return;
  int n0 = n * 128;

  if (t < 128) {
    int r = m0 + t;
    toks[t] = (r < count) ? toklist[z * CAPP + r] : N_TOK;   // pad -> zero row
  }
  __syncthreads();

  int lane = t & 63, w = t >> 6;
  int l8 = lane >> 3, u8 = lane & 7;

  const _Float16* ag[4]; _Float16* al[4];
#pragma unroll
  for (int s = 0; s < 4; s++) {
    int row = w * 32 + s * 8 + l8;
    ag[s] = xh + (long)toks[row] * DDIM + ((u8 ^ (row & 7)) * 8);
    al[s] = As + row * 64 + u8 * 8;
  }
  const _Float16* bg[8]; _Float16* bl[8];
#pragma unroll
  for (int s = 0; s < 8; s++) {
    int rb = w * 64 + s * 8 + l8;
    int gr = (rb < 128) ? (n0 + rb) : (2048 + n0 + (rb - 128));
    bg[s] = w1t + ((long)e * 4096 + gr) * DDIM + ((u8 ^ (rb & 7)) * 8);
    bl[s] = Bs + rb * 64 + u8 * 8;
  }

  int q = lane >> 4, m16 = lane & 15;
  int wm = w & 1, wn = w >> 1;

  f4 zero4 = {0.f, 0.f, 0.f, 0.f};
  f4 acc[4][4][2];
#pragma unroll
  for (int rt = 0; rt < 4; rt++)
#pragma unroll
    for (int ct = 0; ct < 4; ct++) { acc[rt][ct][0] = zero4; acc[rt][ct][1] = zero4; }

  for (int kk = 0; kk < DDIM; kk += 64) {
    __syncthreads();
#pragma unroll
    for (int s = 0; s < 4; s++) { gld16(ag[s], al[s]); ag[s] += 64; }
#pragma unroll
    for (int s = 0; s < 8; s++) { gld16(bg[s], bl[s]); bg[s] += 64; }
    __syncthreads();

#pragma unroll
    for (int c = 0; c < 2; c++) {
      half8 af[4], bf[4][2];
#pragma unroll
      for (int rt = 0; rt < 4; rt++) {
        int row = wm * 64 + rt * 16 + m16;
        af[rt] = *(const half8*)(As + row * 64 + (((c * 4 + q) ^ (row & 7)) * 8));
      }
#pragma unroll
      for (int ct = 0; ct < 4; ct++) {
        int cb = wn * 64 + ct * 16 + m16;
        int ph = ((c * 4 + q) ^ (cb & 7)) * 8;    // (cb+128)&7 == cb&7
        bf[ct][0] = *(const half8*)(Bs + cb * 64 + ph);
        bf[ct][1] = *(const half8*)(Bs + (128 + cb) * 64 + ph);
      }
#pragma unroll
      for (int rt = 0; rt < 4; rt++)
#pragma unroll
        for (int ct = 0; ct < 4; ct++) {
          acc[rt][ct][0] = __builtin_amdgcn_mfma_f32_16x16x32_f16(af[rt], bf[ct][0], acc[rt][ct][0], 0, 0, 0);
          acc[rt][ct][1] = __builtin_amdgcn_mfma_f32_16x16x32_f16(af[rt], bf[ct][1], acc[rt][ct][1], 0, 0, 0);
        }
    }
  }

  long ab = (long)z * CAPP * HDIM;
#pragma unroll
  for (int rt = 0; rt < 4; rt++)
#pragma unroll
    for (int ct = 0; ct < 4; ct++)
#pragma unroll
      for (int r = 0; r < 4; r++) {
        int row = m0 + wm * 64 + rt * 16 + q * 4 + r;   // C/D: row = quad*4+reg
        int col = n0 + wn * 64 + ct * 16 + m16;         //      col = lane&15
        float h1 = acc[rt][ct][0][r], h2 = acc[rt][ct][1][r];
        float s = h2 / (1.f + __expf(-h2));
        act[ab + (long)row * HDIM + col] = (_Float16)(h1 * s);
      }
}

// -------------------- GEMM2: plain fp32 stores into ybuf (no atomics) --------------------
__global__ __launch_bounds__(256, 3) void gemm2_kernel(const _Float16* __restrict__ act,
                                                       const _Float16* __restrict__ w2t,
                                                       const int* __restrict__ counts,
                                                       float* __restrict__ ybuf) {
  int i = blockIdx.x;
  int xcd = i & 7, j = i >> 3;       // 480 blocks, 60/xcd
  int m = j % 5, t2 = j / 5;         // t2<12: k=t2&1, n=t2>>1 (0..5)
  int k = t2 & 1, n = t2 >> 1;
  int e = xcd, z = k * 8 + e;
  int count = counts[z];
  int m0 = m * 128;
  if (m0 >= count) return;
  int n0 = n * 128;

  __shared__ _Float16 As[128 * 64];   // 16 KB
  __shared__ _Float16 Bs[128 * 64];   // 16 KB

  int t = threadIdx.x;
  int lane = t & 63, w = t >> 6;
  int l8 = lane >> 3, u8 = lane & 7;

  const _Float16* ag[4]; _Float16* al[4];
#pragma unroll
  for (int s = 0; s < 4; s++) {
    int row = w * 32 + s * 8 + l8;
    ag[s] = act + ((long)z * CAPP + m0 + row) * HDIM + ((u8 ^ (row & 7)) * 8);
    al[s] = As + row * 64 + u8 * 8;
  }
  const _Float16* bg[4]; _Float16* bl[4];
#pragma unroll
  for (int s = 0; s < 4; s++) {
    int rb = w * 32 + s * 8 + l8;
    bg[s] = w2t + ((long)e * DDIM + n0 + rb) * HDIM + ((u8 ^ (rb & 7)) * 8);
    bl[s] = Bs + rb * 64 + u8 * 8;
  }

  int q = lane >> 4, m16 = lane & 15;
  int wm = w & 1, wn = w >> 1;

  f4 zero4 = {0.f, 0.f, 0.f, 0.f};
  f4 acc[4][4];
#pragma unroll
  for (int rt = 0; rt < 4; rt++)
#pragma unroll
    for (int ct = 0; ct < 4; ct++) acc[rt][ct] = zero4;

  for (int kk = 0; kk < HDIM; kk += 64) {
    __syncthreads();
#pragma unroll
    for (int s = 0; s < 4; s++) { gld16(ag[s], al[s]); ag[s] += 64; }
#pragma unroll
    for (int s = 0; s < 4; s++) { gld16(bg[s], bl[s]); bg[s] += 64; }
    __syncthreads();

#pragma unroll
    for (int c = 0; c < 2; c++) {
      half8 af[4], bf[4];
#pragma unroll
      for (int rt = 0; rt < 4; rt++) {
        int row = wm * 64 + rt * 16 + m16;
        af[rt] = *(const half8*)(As + row * 64 + (((c * 4 + q) ^ (row & 7)) * 8));
      }
#pragma unroll
      for (int ct = 0; ct < 4; ct++) {
        int cb = wn * 64 + ct * 16 + m16;
        bf[ct] = *(const half8*)(Bs + cb * 64 + (((c * 4 + q) ^ (cb & 7)) * 8));
      }
#pragma unroll
      for (int rt = 0; rt < 4; rt++)
#pragma unroll
        for (int ct = 0; ct < 4; ct++)
          acc[rt][ct] = __builtin_amdgcn_mfma_f32_16x16x32_f16(af[rt], bf[ct], acc[rt][ct], 0, 0, 0);
    }
  }

  // plain stores: ybuf[slot][col] = y (padded slots written, never gathered)
#pragma unroll
  for (int rt = 0; rt < 4; rt++)
#pragma unroll
    for (int ct = 0; ct < 4; ct++)
#pragma unroll
      for (int r = 0; r < 4; r++) {
        int lr = wm * 64 + rt * 16 + q * 4 + r;
        int col = n0 + wn * 64 + ct * 16 + m16;
        ybuf[((long)z * CAPP + m0 + lr) * DDIM + col] = acc[rt][ct][r];
      }
}

// -------------------- gather: out[tok] = sum_k w_k * ybuf[slot_k] --------------------
// 1024 blocks x 4 tokens; lane handles 12 floats (3x f4). Replaces memset.
__global__ __launch_bounds__(256) void gather_kernel(const float* __restrict__ ybuf,
                                                     const int* __restrict__ inv,
                                                     const float* __restrict__ wts,
                                                     float* __restrict__ out) {
  int t = threadIdx.x;
  int w = t >> 6, lane = t & 63;
  int tok = blockIdx.x * 4 + w;
  int s0 = inv[tok * 2 + 0], s1 = inv[tok * 2 + 1];
  float w0 = wts[tok * 2 + 0], w1 = wts[tok * 2 + 1];
  float acc[12];
#pragma unroll
  for (int j = 0; j < 12; j++) acc[j] = 0.f;
  int b = lane * 12;
  if (s0 >= 0) {
    const float* y = ybuf + (long)s0 * DDIM + b;
#pragma unroll
    for (int v = 0; v < 3; v++) {
      f4 qv = *(const f4*)(y + v * 4);
#pragma unroll
      for (int j = 0; j < 4; j++) acc[v * 4 + j] += w0 * qv[j];
    }
  }
  if (s1 >= 0) {
    const float* y = ybuf + (long)s1 * DDIM + b;
#pragma unroll
    for (int v = 0; v < 3; v++) {
      f4 qv = *(const f4*)(y + v * 4);
#pragma unroll
      for (int j = 0; j < 4; j++) acc[v * 4 + j] += w1 * qv[j];
    }
  }
  float* o = out + (long)tok * DDIM + b;
#pragma unroll
  for (int v = 0; v < 3; v++) {
    f4 qv;
#pragma unroll
    for (int j = 0; j < 4; j++) qv[j] = acc[v * 4 + j];
    *(f4*)(o + v * 4) = qv;
  }
}

// -------------------- launch --------------------

extern "C" void kernel_launch(void* const* d_in, const int* in_sizes, int n_in,
                              void* d_out, int out_size, void* d_ws, size_t ws_size,
                              hipStream_t stream) {
  const float* x  = (const float*)d_in[0];
  const float* Wg = (const float*)d_in[1];
  const float* W1 = (const float*)d_in[2];
  const float* W2 = (const float*)d_in[3];
  float* out = (float*)d_out;
  char* ws = (char*)d_ws;

  _Float16* xh   = (_Float16*)(ws + XH_OFF);
  _Float16* w1t  = (_Float16*)(ws + W1T_OFF);
  float*    ybuf = (float*)(ws + YB_OFF);
  _Float16* w2t  = (_Float16*)(ws + W2T_OFF);
  _Float16* actb = (_Float16*)(ws + ACT_OFF);
  int* eidx      = (int*)(ws + EIDX_OFF);
  float* wts     = (float*)(ws + WTS_OFF);
  int* toklist   = (int*)(ws + TOKL_OFF);
  int* counts    = (int*)(ws + CNT_OFF);
  int* inv       = (int*)(ws + INV_OFF);

  prep1_kernel<<<2561, 256, 0, stream>>>(W1, x, Wg, w1t, xh, eidx, wts);
  scan_kernel<<<16, 64, 0, stream>>>(eidx, toklist, counts, inv);
  gemm1_kernel<<<2816, 256, 0, stream>>>(xh, w1t, W2, w2t, toklist, counts, actb);
  gemm2_kernel<<<480, 256, 0, stream>>>(actb, w2t, counts, ybuf);
  gather_kernel<<<1024, 256, 0, stream>>>(ybuf, inv, wts, out);
}

// Round 7
// 342.279 us; speedup vs baseline: 1.1017x; 1.1017x over previous
//
#include <hip/hip_runtime.h>

// GatedMoE on MI355X (gfx950), fp16 MFMA path, round 11.
// vs r10 (regressed): interleaving cvt-W2 with gemm1 displaced gemm1 from
// CU residency (MfmaUtil 27->18.6, dur 87->123). r11 reverts to r9's
// APPEND mapping (cvt-W2 blocks after gemm1 blocks -> they only fill CUs
// as gemm1 drains). Keeps r10's two other changes: wave-private barrier-
// free cvt (0 bank conflicts) and de-atomized gemm2 (plain stores to ybuf
// + inv map + gather kernel; no memset dispatch).

typedef _Float16 half8 __attribute__((ext_vector_type(8)));
typedef _Float16 half4t __attribute__((ext_vector_type(4)));
typedef float f4 __attribute__((ext_vector_type(4)));

#define N_TOK 4096
#define DDIM  768
#define HDIM  2048
#define NEXP  8
#define CAP   614   // int(1.2 * 4096 / 8)
#define CAPP  640

// ---- workspace layout (bytes) ----
#define XH_OFF    0L           // (4097*768) fp16
#define W1T_OFF   6292992L     // [8][4096][768] fp16 (dead after gemm1)
#define YB_OFF    6292992L     // [16][640][768] fp32 ybuf (gemm2->gather), aliases w1t
#define W2T_OFF   56624640L    // [8][768][2048] fp16
#define ACT_OFF   81790464L    // [16][640][2048] fp16
#define EIDX_OFF  123733504L   // [4096][2] int
#define WTS_OFF   123766272L   // [4096][2] float
#define TOKL_OFF  123799040L   // [16][640] int
#define CNT_OFF   123840000L   // [16] int
#define INV_OFF   123840256L   // [4096][2] int (tok,k) -> z*CAPP+slot | -1

__device__ __forceinline__ void gld16(const void* g, void* l) {
  __builtin_amdgcn_global_load_lds(
      (const __attribute__((address_space(1))) unsigned int*)g,
      (__attribute__((address_space(3))) unsigned int*)l, 16, 0, 0);
}

// -------------------- wave-private transpose+convert --------------------
// 64x64 fp32 tile -> fp16 transposed. No block barrier: wave owns its tile.
__device__ __forceinline__ void cvt_wave64(const float* __restrict__ src,
                                           _Float16* __restrict__ dst,
                                           int R, int C, int e, int r0, int c0,
                                           float* __restrict__ wt, int lane) {
  long sb = (long)e * R * C;
  int lr = lane >> 4, l4 = (lane & 15) * 4;
#pragma unroll
  for (int s = 0; s < 16; s++) {
    int row = s * 4 + lr;
    f4 v = *(const f4*)(src + sb + (long)(r0 + row) * C + c0 + l4);
    *(f4*)(&wt[row * 68 + l4]) = v;
  }
  asm volatile("s_waitcnt lgkmcnt(0)" ::: "memory");   // own wave's LDS writes done
  int c = lane;
#pragma unroll
  for (int ch = 0; ch < 8; ch++) {
    half8 h;
#pragma unroll
    for (int j = 0; j < 8; j++) h[j] = (_Float16)wt[(ch * 8 + j) * 68 + c];
    *(half8*)(dst + sb + (long)(c0 + c) * R + r0 + ch * 8) = h;
  }
}

// 64x32 variant (fits in gemm1's LDS budget): 9216 B/wave.
__device__ __forceinline__ void cvt_wave32(const float* __restrict__ src,
                                           _Float16* __restrict__ dst,
                                           int R, int C, int e, int r0, int c0,
                                           float* __restrict__ wt, int lane) {
  long sb = (long)e * R * C;
  int r8 = lane >> 3, l4 = (lane & 7) * 4;
#pragma unroll
  for (int s = 0; s < 8; s++) {
    int row = s * 8 + r8;
    f4 v = *(const f4*)(src + sb + (long)(r0 + row) * C + c0 + l4);
    *(f4*)(&wt[row * 36 + l4]) = v;
  }
  asm volatile("s_waitcnt lgkmcnt(0)" ::: "memory");
  int c = lane & 31, h2 = lane >> 5;
#pragma unroll
  for (int ch = 0; ch < 4; ch++) {
    half8 h;
#pragma unroll
    for (int j = 0; j < 8; j++) h[j] = (_Float16)wt[(h2 * 32 + ch * 8 + j) * 36 + c];
    *(half8*)(dst + sb + (long)(c0 + c) * R + r0 + h2 * 32 + ch * 8) = h;
  }
}

// -------------------- prep1: router | cvt_tr(W1) --------------------
// blocks [0,1025): router + x->fp16; [1025,2561): W1 cvt (64x256/block, 4 waves)
__global__ __launch_bounds__(256) void prep1_kernel(const float* __restrict__ W1,
                                                    const float* __restrict__ x,
                                                    const float* __restrict__ Wg,
                                                    _Float16* __restrict__ w1t,
                                                    _Float16* __restrict__ xh,
                                                    int* __restrict__ eidx,
                                                    float* __restrict__ wts) {
  __shared__ float pls[4 * 64 * 68];   // 69.6 KB (4 wave tiles) / wgT (24 KB)
  int b = blockIdx.x;
  int t = threadIdx.x;
  int w = t >> 6, lane = t & 63;

  if (b >= 1025) {                     // ---- cvt W1: 768x4096 per expert
    int cb = b - 1025;                 // 0..1535
    int e = cb / 192, rem = cb % 192;  // 12 r-tiles x 16 c256-tiles
    int cx = rem % 12, cy = rem / 12;
    cvt_wave64(W1, w1t, 768, 4096, e, cx * 64, cy * 256 + w * 64, pls + w * (64 * 68), lane);
    return;
  }

  // ---- router
  for (int i = t; i < DDIM * NEXP; i += 256) pls[(i & 7) * DDIM + (i >> 3)] = Wg[i];
  __syncthreads();
  int tok = b * 4 + w;
  if (tok > N_TOK) return;
  if (tok == N_TOK) {                  // zero pad row
    half4t zz; zz[0] = zz[1] = zz[2] = zz[3] = (_Float16)0.f;
#pragma unroll
    for (int j = 0; j < 3; j++) *(half4t*)(xh + (long)N_TOK * DDIM + (lane + j * 64) * 4) = zz;
    return;
  }
  const float* xr = x + (long)tok * DDIM;
#pragma unroll
  for (int j = 0; j < 3; j++) {
    f4 v = *(const f4*)(xr + (lane + j * 64) * 4);
    half4t hv;
    hv[0] = (_Float16)v[0]; hv[1] = (_Float16)v[1];
    hv[2] = (_Float16)v[2]; hv[3] = (_Float16)v[3];
    *(half4t*)(xh + (long)tok * DDIM + (lane + j * 64) * 4) = hv;
  }
  float acc[8] = {0.f, 0.f, 0.f, 0.f, 0.f, 0.f, 0.f, 0.f};
#pragma unroll
  for (int i = 0; i < 12; i++) {
    float xv = xr[i * 64 + lane];
#pragma unroll
    for (int e2 = 0; e2 < 8; e2++) acc[e2] += xv * pls[e2 * DDIM + i * 64 + lane];
  }
#pragma unroll
  for (int e2 = 0; e2 < 8; e2++) {
    float v = acc[e2];
    v += __shfl_xor(v, 32); v += __shfl_xor(v, 16); v += __shfl_xor(v, 8);
    v += __shfl_xor(v, 4);  v += __shfl_xor(v, 2);  v += __shfl_xor(v, 1);
    acc[e2] = v;
  }
  if (lane == 0) {
    float m0 = -1e30f; int i0 = 0;
#pragma unroll
    for (int e2 = 0; e2 < 8; e2++) if (acc[e2] > m0) { m0 = acc[e2]; i0 = e2; }
    float m1 = -1e30f; int i1 = 0;
#pragma unroll
    for (int e2 = 0; e2 < 8; e2++) if (e2 != i0 && acc[e2] > m1) { m1 = acc[e2]; i1 = e2; }
    float tt = __expf(m1 - m0);
    float w0 = 1.f / (1.f + tt);
    eidx[tok * 2 + 0] = i0; eidx[tok * 2 + 1] = i1;
    wts[tok * 2 + 0] = w0;  wts[tok * 2 + 1] = 1.f - w0;
  }
}

// -------------------- capacity scan (+ inverse map) --------------------
__global__ __launch_bounds__(64) void scan_kernel(const int* __restrict__ eidx,
                                                  int* __restrict__ toklist,
                                                  int* __restrict__ counts,
                                                  int* __restrict__ inv) {
  int z = blockIdx.x;
  int k = z >> 3, e = z & 7;
  int lane = threadIdx.x;
  int mye[64];
#pragma unroll
  for (int c = 0; c < 64; c++) mye[c] = eidx[(c * 64 + lane) * 2 + k];
  int base = 0;
#pragma unroll 4
  for (int c = 0; c < 64; c++) {
    int n = c * 64 + lane;
    bool pred = (mye[c] == e);
    unsigned long long mask = __ballot(pred);
    if (pred) {
      int pos = base + __popcll(mask & ((1ull << lane) - 1ull));
      if (pos < CAP) {
        toklist[z * CAPP + pos] = n;
        inv[n * 2 + k] = z * CAPP + pos;
      } else {
        inv[n * 2 + k] = -1;              // capacity-dropped
      }
    }
    base += __popcll(mask);
  }
  if (lane == 0) counts[z] = (base < CAP) ? base : CAP;
}

// -------------------- GEMM1 + fused SwiGLU | appended cvt_tr(W2) --------------------
// blocks [0,1280): gemm1 (r4 structure). blocks [1280,2816): cvt W2
// (appended: they only occupy CUs as gemm1 drains -> tail, not displacement).
__global__ __launch_bounds__(256, 2) void gemm1_kernel(const _Float16* __restrict__ xh,
                                                       const _Float16* __restrict__ w1t,
                                                       const float* __restrict__ W2,
                                                       _Float16* __restrict__ w2t,
                                                       const int* __restrict__ toklist,
                                                       const int* __restrict__ counts,
                                                       _Float16* __restrict__ act) {
  __shared__ float smemf[12416];   // 49664 B: gemm1 As|Bs|toks, cvt: 4x9216 B

  int t = threadIdx.x;
  int i = blockIdx.x;

  if (i >= 1280) {                   // ---- cvt W2: 2048x768 per expert
    int ci = i - 1280;               // 0..1535
    int e = ci / 192, rem = ci % 192;  // 32 r-tiles x 6 c128-tiles
    int cx = rem % 32, cc = rem / 32;
    int w = t >> 6, lane = t & 63;
    cvt_wave32(W2, w2t, 2048, 768, e, cx * 64, cc * 128 + w * 32, smemf + w * 2304, lane);
    return;
  }

  _Float16* As = (_Float16*)smemf;             // 128*64
  _Float16* Bs = (_Float16*)(smemf + 4096);    // 256*64
  int* toks = (int*)(smemf + 12288);           // 128

  int xcd = i & 7, j = i >> 3;       // 1280 gemm1 blocks, 160/xcd
  int m = j % 5, ii = j / 5;
  int k = ii & 1, n = ii >> 1;
  int e = xcd, z = k * 8 + e;
  int count = counts[z];
  int m0 = m * 128;
  if (m0 >= count) return;
  int n0 = n * 128;

  if (t < 128) {
    int r = m0 + t;
    toks[t] = (r < count) ? toklist[z * CAPP + r] : N_TOK;   // pad -> zero row
  }
  __syncthreads();

  int lane = t & 63, w = t >> 6;
  int l8 = lane >> 3, u8 = lane & 7;

  const _Float16* ag[4]; _Float16* al[4];
#pragma unroll
  for (int s = 0; s < 4; s++) {
    int row = w * 32 + s * 8 + l8;
    ag[s] = xh + (long)toks[row] * DDIM + ((u8 ^ (row & 7)) * 8);
    al[s] = As + row * 64 + u8 * 8;
  }
  const _Float16* bg[8]; _Float16* bl[8];
#pragma unroll
  for (int s = 0; s < 8; s++) {
    int rb = w * 64 + s * 8 + l8;
    int gr = (rb < 128) ? (n0 + rb) : (2048 + n0 + (rb - 128));
    bg[s] = w1t + ((long)e * 4096 + gr) * DDIM + ((u8 ^ (rb & 7)) * 8);
    bl[s] = Bs + rb * 64 + u8 * 8;
  }

  int q = lane >> 4, m16 = lane & 15;
  int wm = w & 1, wn = w >> 1;

  f4 zero4 = {0.f, 0.f, 0.f, 0.f};
  f4 acc[4][4][2];
#pragma unroll
  for (int rt = 0; rt < 4; rt++)
#pragma unroll
    for (int ct = 0; ct < 4; ct++) { acc[rt][ct][0] = zero4; acc[rt][ct][1] = zero4; }

  for (int kk = 0; kk < DDIM; kk += 64) {
    __syncthreads();
#pragma unroll
    for (int s = 0; s < 4; s++) { gld16(ag[s], al[s]); ag[s] += 64; }
#pragma unroll
    for (int s = 0; s < 8; s++) { gld16(bg[s], bl[s]); bg[s] += 64; }
    __syncthreads();

#pragma unroll
    for (int c = 0; c < 2; c++) {
      half8 af[4], bf[4][2];
#pragma unroll
      for (int rt = 0; rt < 4; rt++) {
        int row = wm * 64 + rt * 16 + m16;
        af[rt] = *(const half8*)(As + row * 64 + (((c * 4 + q) ^ (row & 7)) * 8));
      }
#pragma unroll
      for (int ct = 0; ct < 4; ct++) {
        int cb = wn * 64 + ct * 16 + m16;
        int ph = ((c * 4 + q) ^ (cb & 7)) * 8;    // (cb+128)&7 == cb&7
        bf[ct][0] = *(const half8*)(Bs + cb * 64 + ph);
        bf[ct][1] = *(const half8*)(Bs + (128 + cb) * 64 + ph);
      }
#pragma unroll
      for (int rt = 0; rt < 4; rt++)
#pragma unroll
        for (int ct = 0; ct < 4; ct++) {
          acc[rt][ct][0] = __builtin_amdgcn_mfma_f32_16x16x32_f16(af[rt], bf[ct][0], acc[rt][ct][0], 0, 0, 0);
          acc[rt][ct][1] = __builtin_amdgcn_mfma_f32_16x16x32_f16(af[rt], bf[ct][1], acc[rt][ct][1], 0, 0, 0);
        }
    }
  }

  long ab = (long)z * CAPP * HDIM;
#pragma unroll
  for (int rt = 0; rt < 4; rt++)
#pragma unroll
    for (int ct = 0; ct < 4; ct++)
#pragma unroll
      for (int r = 0; r < 4; r++) {
        int row = m0 + wm * 64 + rt * 16 + q * 4 + r;   // C/D: row = quad*4+reg
        int col = n0 + wn * 64 + ct * 16 + m16;         //      col = lane&15
        float h1 = acc[rt][ct][0][r], h2 = acc[rt][ct][1][r];
        float s = h2 / (1.f + __expf(-h2));
        act[ab + (long)row * HDIM + col] = (_Float16)(h1 * s);
      }
}

// -------------------- GEMM2: plain fp32 stores into ybuf (no atomics) --------------------
__global__ __launch_bounds__(256, 3) void gemm2_kernel(const _Float16* __restrict__ act,
                                                       const _Float16* __restrict__ w2t,
                                                       const int* __restrict__ counts,
                                                       float* __restrict__ ybuf) {
  int i = blockIdx.x;
  int xcd = i & 7, j = i >> 3;       // 480 blocks, 60/xcd
  int m = j % 5, t2 = j / 5;         // t2<12: k=t2&1, n=t2>>1 (0..5)
  int k = t2 & 1, n = t2 >> 1;
  int e = xcd, z = k * 8 + e;
  int count = counts[z];
  int m0 = m * 128;
  if (m0 >= count) return;
  int n0 = n * 128;

  __shared__ _Float16 As[128 * 64];   // 16 KB
  __shared__ _Float16 Bs[128 * 64];   // 16 KB

  int t = threadIdx.x;
  int lane = t & 63, w = t >> 6;
  int l8 = lane >> 3, u8 = lane & 7;

  const _Float16* ag[4]; _Float16* al[4];
#pragma unroll
  for (int s = 0; s < 4; s++) {
    int row = w * 32 + s * 8 + l8;
    ag[s] = act + ((long)z * CAPP + m0 + row) * HDIM + ((u8 ^ (row & 7)) * 8);
    al[s] = As + row * 64 + u8 * 8;
  }
  const _Float16* bg[4]; _Float16* bl[4];
#pragma unroll
  for (int s = 0; s < 4; s++) {
    int rb = w * 32 + s * 8 + l8;
    bg[s] = w2t + ((long)e * DDIM + n0 + rb) * HDIM + ((u8 ^ (rb & 7)) * 8);
    bl[s] = Bs + rb * 64 + u8 * 8;
  }

  int q = lane >> 4, m16 = lane & 15;
  int wm = w & 1, wn = w >> 1;

  f4 zero4 = {0.f, 0.f, 0.f, 0.f};
  f4 acc[4][4];
#pragma unroll
  for (int rt = 0; rt < 4; rt++)
#pragma unroll
    for (int ct = 0; ct < 4; ct++) acc[rt][ct] = zero4;

  for (int kk = 0; kk < HDIM; kk += 64) {
    __syncthreads();
#pragma unroll
    for (int s = 0; s < 4; s++) { gld16(ag[s], al[s]); ag[s] += 64; }
#pragma unroll
    for (int s = 0; s < 4; s++) { gld16(bg[s], bl[s]); bg[s] += 64; }
    __syncthreads();

#pragma unroll
    for (int c = 0; c < 2; c++) {
      half8 af[4], bf[4];
#pragma unroll
      for (int rt = 0; rt < 4; rt++) {
        int row = wm * 64 + rt * 16 + m16;
        af[rt] = *(const half8*)(As + row * 64 + (((c * 4 + q) ^ (row & 7)) * 8));
      }
#pragma unroll
      for (int ct = 0; ct < 4; ct++) {
        int cb = wn * 64 + ct * 16 + m16;
        bf[ct] = *(const half8*)(Bs + cb * 64 + (((c * 4 + q) ^ (cb & 7)) * 8));
      }
#pragma unroll
      for (int rt = 0; rt < 4; rt++)
#pragma unroll
        for (int ct = 0; ct < 4; ct++)
          acc[rt][ct] = __builtin_amdgcn_mfma_f32_16x16x32_f16(af[rt], bf[ct], acc[rt][ct], 0, 0, 0);
    }
  }

  // plain stores: ybuf[slot][col] = y (padded slots written, never gathered)
#pragma unroll
  for (int rt = 0; rt < 4; rt++)
#pragma unroll
    for (int ct = 0; ct < 4; ct++)
#pragma unroll
      for (int r = 0; r < 4; r++) {
        int lr = wm * 64 + rt * 16 + q * 4 + r;
        int col = n0 + wn * 64 + ct * 16 + m16;
        ybuf[((long)z * CAPP + m0 + lr) * DDIM + col] = acc[rt][ct][r];
      }
}

// -------------------- gather: out[tok] = sum_k w_k * ybuf[slot_k] --------------------
__global__ __launch_bounds__(256) void gather_kernel(const float* __restrict__ ybuf,
                                                     const int* __restrict__ inv,
                                                     const float* __restrict__ wts,
                                                     float* __restrict__ out) {
  int t = threadIdx.x;
  int w = t >> 6, lane = t & 63;
  int tok = blockIdx.x * 4 + w;
  int s0 = inv[tok * 2 + 0], s1 = inv[tok * 2 + 1];
  float w0 = wts[tok * 2 + 0], w1 = wts[tok * 2 + 1];
  float acc[12];
#pragma unroll
  for (int j = 0; j < 12; j++) acc[j] = 0.f;
  int b = lane * 12;
  if (s0 >= 0) {
    const float* y = ybuf + (long)s0 * DDIM + b;
#pragma unroll
    for (int v = 0; v < 3; v++) {
      f4 qv = *(const f4*)(y + v * 4);
#pragma unroll
      for (int j = 0; j < 4; j++) acc[v * 4 + j] += w0 * qv[j];
    }
  }
  if (s1 >= 0) {
    const float* y = ybuf + (long)s1 * DDIM + b;
#pragma unroll
    for (int v = 0; v < 3; v++) {
      f4 qv = *(const f4*)(y + v * 4);
#pragma unroll
      for (int j = 0; j < 4; j++) acc[v * 4 + j] += w1 * qv[j];
    }
  }
  float* o = out + (long)tok * DDIM + b;
#pragma unroll
  for (int v = 0; v < 3; v++) {
    f4 qv;
#pragma unroll
    for (int j = 0; j < 4; j++) qv[j] = acc[v * 4 + j];
    *(f4*)(o + v * 4) = qv;
  }
}

// -------------------- launch --------------------

extern "C" void kernel_launch(void* const* d_in, const int* in_sizes, int n_in,
                              void* d_out, int out_size, void* d_ws, size_t ws_size,
                              hipStream_t stream) {
  const float* x  = (const float*)d_in[0];
  const float* Wg = (const float*)d_in[1];
  const float* W1 = (const float*)d_in[2];
  const float* W2 = (const float*)d_in[3];
  float* out = (float*)d_out;
  char* ws = (char*)d_ws;

  _Float16* xh   = (_Float16*)(ws + XH_OFF);
  _Float16* w1t  = (_Float16*)(ws + W1T_OFF);
  float*    ybuf = (float*)(ws + YB_OFF);
  _Float16* w2t  = (_Float16*)(ws + W2T_OFF);
  _Float16* actb = (_Float16*)(ws + ACT_OFF);
  int* eidx      = (int*)(ws + EIDX_OFF);
  float* wts     = (float*)(ws + WTS_OFF);
  int* toklist   = (int*)(ws + TOKL_OFF);
  int* counts    = (int*)(ws + CNT_OFF);
  int* inv       = (int*)(ws + INV_OFF);

  prep1_kernel<<<2561, 256, 0, stream>>>(W1, x, Wg, w1t, xh, eidx, wts);
  scan_kernel<<<16, 64, 0, stream>>>(eidx, toklist, counts, inv);
  gemm1_kernel<<<2816, 256, 0, stream>>>(xh, w1t, W2, w2t, toklist, counts, actb);
  gemm2_kernel<<<480, 256, 0, stream>>>(actb, w2t, counts, ybuf);
  gather_kernel<<<1024, 256, 0, stream>>>(ybuf, inv, wts, out);
}

// Round 8
// 331.321 us; speedup vs baseline: 1.1381x; 1.0331x over previous
//
#include <hip/hip_runtime.h>

// GatedMoE on MI355X (gfx950), fp16 MFMA path, round 12.
// vs r11 (regressed): wave-private cvt wrote 16-B scattered segments per
// lane -> W2 tail grew 17us. r12 reverts ALL converts to the proven
// block-coop cvt2_tile (64x128, 8 f4 in flight, 128-B write segments,
// r9's code). Keeps r11's de-atomized gemm2 (plain stores to ybuf) +
// inv map + gather (no memset dispatch). This isolates de-atomization
// against r9's 332us baseline.

typedef _Float16 half8 __attribute__((ext_vector_type(8)));
typedef _Float16 half4t __attribute__((ext_vector_type(4)));
typedef float f4 __attribute__((ext_vector_type(4)));

#define N_TOK 4096
#define DDIM  768
#define HDIM  2048
#define NEXP  8
#define CAP   614   // int(1.2 * 4096 / 8)
#define CAPP  640

// ---- workspace layout (bytes) ----
#define XH_OFF    0L           // (4097*768) fp16
#define W1T_OFF   6292992L     // [8][4096][768] fp16 (dead after gemm1)
#define YB_OFF    6292992L     // [16][640][768] fp32 ybuf (gemm2->gather), aliases w1t
#define W2T_OFF   56624640L    // [8][768][2048] fp16
#define ACT_OFF   81790464L    // [16][640][2048] fp16
#define EIDX_OFF  123733504L   // [4096][2] int
#define WTS_OFF   123766272L   // [4096][2] float
#define TOKL_OFF  123799040L   // [16][640] int
#define CNT_OFF   123840000L   // [16] int
#define INV_OFF   123840256L   // [4096][2] int (tok,k) -> z*CAPP+slot | -1

__device__ __forceinline__ void gld16(const void* g, void* l) {
  __builtin_amdgcn_global_load_lds(
      (const __attribute__((address_space(1))) unsigned int*)g,
      (__attribute__((address_space(3))) unsigned int*)l, 16, 0, 0);
}

// -------------------- wide transpose+convert: 64 rows x 128 cols --------------------
// src fp32 [e][R][C] tile at (r0, c0) -> dst fp16 [e][C][R]. Block-coop:
// loads 8 f4/thread in flight; writes 128-B contiguous segments per 8 lanes.
__device__ __forceinline__ void cvt2_tile(const float* __restrict__ src,
                                          _Float16* __restrict__ dst,
                                          int R, int C, int e, int r0, int c0,
                                          float* __restrict__ tile) {
  long sb = (long)e * R * C;
  int t = threadIdx.x;
  int rrow = t >> 4, c4 = (t & 15) * 4;
#pragma unroll
  for (int h = 0; h < 2; h++)
#pragma unroll
    for (int i = 0; i < 4; i++) {
      int row = i * 16 + rrow;
      f4 v = *(const f4*)(src + sb + (long)(r0 + row) * C + c0 + h * 64 + c4);
      *(f4*)(&tile[h * 4416 + row * 69 + c4]) = v;
    }
  __syncthreads();
#pragma unroll
  for (int h = 0; h < 2; h++)
#pragma unroll
    for (int s = 0; s < 2; s++) {
      int idx = t + s * 256;
      int c = idx >> 3, ch = idx & 7;
      half8 hv;
#pragma unroll
      for (int j = 0; j < 8; j++) hv[j] = (_Float16)tile[h * 4416 + (ch * 8 + j) * 69 + c];
      *(half8*)(dst + sb + (long)(c0 + h * 64 + c) * R + r0 + ch * 8) = hv;
    }
}

// -------------------- prep1: cvt_tr(W1) | router --------------------
// blocks [0,3072): W1 [8][768][4096] fp32 -> w1t fp16 (64x128 tiles)
// blocks [3072,4097): router + x->fp16 convert (4 tokens/block)
__global__ __launch_bounds__(256) void prep1_kernel(const float* __restrict__ W1,
                                                    const float* __restrict__ x,
                                                    const float* __restrict__ Wg,
                                                    _Float16* __restrict__ w1t,
                                                    _Float16* __restrict__ xh,
                                                    int* __restrict__ eidx,
                                                    float* __restrict__ wts) {
  __shared__ float smem[2 * 4416];   // 35.3 KB: cvt tiles or wgT (24 KB)
  int b = blockIdx.x;

  if (b < 3072) {                    // ---- cvt W1
    int e = b / 384, rem = b % 384;
    int cx = rem % 12, cy = rem / 12;       // 12 r-tiles x 32 col2-tiles
    cvt2_tile(W1, w1t, 768, 4096, e, cx * 64, cy * 128, smem);
    return;
  }

  // ---- router (block-uniform path)
  int rb = b - 3072;                 // 0..1024
  int t = threadIdx.x;
  for (int i = t; i < DDIM * NEXP; i += 256) smem[(i & 7) * DDIM + (i >> 3)] = Wg[i];
  __syncthreads();
  int w = t >> 6, lane = t & 63;
  int tok = rb * 4 + w;
  if (tok > N_TOK) return;
  if (tok == N_TOK) {                // zero pad row
    half4t zz; zz[0] = zz[1] = zz[2] = zz[3] = (_Float16)0.f;
#pragma unroll
    for (int j = 0; j < 3; j++) *(half4t*)(xh + (long)N_TOK * DDIM + (lane + j * 64) * 4) = zz;
    return;
  }
  const float* xr = x + (long)tok * DDIM;
#pragma unroll
  for (int j = 0; j < 3; j++) {
    f4 v = *(const f4*)(xr + (lane + j * 64) * 4);
    half4t hv;
    hv[0] = (_Float16)v[0]; hv[1] = (_Float16)v[1];
    hv[2] = (_Float16)v[2]; hv[3] = (_Float16)v[3];
    *(half4t*)(xh + (long)tok * DDIM + (lane + j * 64) * 4) = hv;
  }
  float acc[8] = {0.f, 0.f, 0.f, 0.f, 0.f, 0.f, 0.f, 0.f};
#pragma unroll
  for (int i = 0; i < 12; i++) {
    float xv = xr[i * 64 + lane];
#pragma unroll
    for (int e2 = 0; e2 < 8; e2++) acc[e2] += xv * smem[e2 * DDIM + i * 64 + lane];
  }
#pragma unroll
  for (int e2 = 0; e2 < 8; e2++) {
    float v = acc[e2];
    v += __shfl_xor(v, 32); v += __shfl_xor(v, 16); v += __shfl_xor(v, 8);
    v += __shfl_xor(v, 4);  v += __shfl_xor(v, 2);  v += __shfl_xor(v, 1);
    acc[e2] = v;
  }
  if (lane == 0) {
    float m0 = -1e30f; int i0 = 0;
#pragma unroll
    for (int e2 = 0; e2 < 8; e2++) if (acc[e2] > m0) { m0 = acc[e2]; i0 = e2; }
    float m1 = -1e30f; int i1 = 0;
#pragma unroll
    for (int e2 = 0; e2 < 8; e2++) if (e2 != i0 && acc[e2] > m1) { m1 = acc[e2]; i1 = e2; }
    float tt = __expf(m1 - m0);
    float w0 = 1.f / (1.f + tt);
    eidx[tok * 2 + 0] = i0; eidx[tok * 2 + 1] = i1;
    wts[tok * 2 + 0] = w0;  wts[tok * 2 + 1] = 1.f - w0;
  }
}

// -------------------- capacity scan (+ inverse map) --------------------
__global__ __launch_bounds__(64) void scan_kernel(const int* __restrict__ eidx,
                                                  int* __restrict__ toklist,
                                                  int* __restrict__ counts,
                                                  int* __restrict__ inv) {
  int z = blockIdx.x;
  int k = z >> 3, e = z & 7;
  int lane = threadIdx.x;
  int mye[64];
#pragma unroll
  for (int c = 0; c < 64; c++) mye[c] = eidx[(c * 64 + lane) * 2 + k];
  int base = 0;
#pragma unroll 4
  for (int c = 0; c < 64; c++) {
    int n = c * 64 + lane;
    bool pred = (mye[c] == e);
    unsigned long long mask = __ballot(pred);
    if (pred) {
      int pos = base + __popcll(mask & ((1ull << lane) - 1ull));
      if (pos < CAP) {
        toklist[z * CAPP + pos] = n;
        inv[n * 2 + k] = z * CAPP + pos;
      } else {
        inv[n * 2 + k] = -1;              // capacity-dropped
      }
    }
    base += __popcll(mask);
  }
  if (lane == 0) counts[z] = (base < CAP) ? base : CAP;
}

// -------------------- GEMM1 + fused SwiGLU | appended cvt_tr(W2) --------------------
// blocks [0,1280): gemm1 (r4 structure). blocks [1280,2816): cvt W2 64x128
// (appended: they only occupy CUs as gemm1 drains -> tail, not displacement).
__global__ __launch_bounds__(256, 2) void gemm1_kernel(const _Float16* __restrict__ xh,
                                                       const _Float16* __restrict__ w1t,
                                                       const float* __restrict__ W2,
                                                       _Float16* __restrict__ w2t,
                                                       const int* __restrict__ toklist,
                                                       const int* __restrict__ counts,
                                                       _Float16* __restrict__ act) {
  __shared__ char smem[49664];   // gemm1: As 16K | Bs 32K | toks 512. cvt: 35.3K

  int i = blockIdx.x;
  if (i >= 1280) {                   // ---- cvt W2: 2048x768 per expert
    int b2 = i - 1280;               // 0..1535
    int e = b2 / 192, rem = b2 % 192;
    int cx = rem % 32, cy = rem / 32;      // 32 r-tiles x 6 col2-tiles
    cvt2_tile(W2, w2t, 2048, 768, e, cx * 64, cy * 128, (float*)smem);
    return;
  }

  _Float16* As = (_Float16*)smem;             // 128*64
  _Float16* Bs = (_Float16*)(smem + 16384);   // 256*64
  int* toks = (int*)(smem + 49152);           // 128

  int xcd = i & 7, j = i >> 3;       // 1280 blocks, 160/xcd
  int m = j % 5, ii = j / 5;
  int k = ii & 1, n = ii >> 1;
  int e = xcd, z = k * 8 + e;
  int count = counts[z];
  int m0 = m * 128;
  if (m0 >= count) return;
  int n0 = n * 128;

  int t = threadIdx.x;
  if (t < 128) {
    int r = m0 + t;
    toks[t] = (r < count) ? toklist[z * CAPP + r] : N_TOK;   // pad -> zero row
  }
  __syncthreads();

  int lane = t & 63, w = t >> 6;
  int l8 = lane >> 3, u8 = lane & 7;

  const _Float16* ag[4]; _Float16* al[4];
#pragma unroll
  for (int s = 0; s < 4; s++) {
    int row = w * 32 + s * 8 + l8;
    ag[s] = xh + (long)toks[row] * DDIM + ((u8 ^ (row & 7)) * 8);
    al[s] = As + row * 64 + u8 * 8;
  }
  const _Float16* bg[8]; _Float16* bl[8];
#pragma unroll
  for (int s = 0; s < 8; s++) {
    int rb = w * 64 + s * 8 + l8;
    int gr = (rb < 128) ? (n0 + rb) : (2048 + n0 + (rb - 128));
    bg[s] = w1t + ((long)e * 4096 + gr) * DDIM + ((u8 ^ (rb & 7)) * 8);
    bl[s] = Bs + rb * 64 + u8 * 8;
  }

  int q = lane >> 4, m16 = lane & 15;
  int wm = w & 1, wn = w >> 1;

  f4 zero4 = {0.f, 0.f, 0.f, 0.f};
  f4 acc[4][4][2];
#pragma unroll
  for (int rt = 0; rt < 4; rt++)
#pragma unroll
    for (int ct = 0; ct < 4; ct++) { acc[rt][ct][0] = zero4; acc[rt][ct][1] = zero4; }

  for (int kk = 0; kk < DDIM; kk += 64) {
    __syncthreads();
#pragma unroll
    for (int s = 0; s < 4; s++) { gld16(ag[s], al[s]); ag[s] += 64; }
#pragma unroll
    for (int s = 0; s < 8; s++) { gld16(bg[s], bl[s]); bg[s] += 64; }
    __syncthreads();

#pragma unroll
    for (int c = 0; c < 2; c++) {
      half8 af[4], bf[4][2];
#pragma unroll
      for (int rt = 0; rt < 4; rt++) {
        int row = wm * 64 + rt * 16 + m16;
        af[rt] = *(const half8*)(As + row * 64 + (((c * 4 + q) ^ (row & 7)) * 8));
      }
#pragma unroll
      for (int ct = 0; ct < 4; ct++) {
        int cb = wn * 64 + ct * 16 + m16;
        int ph = ((c * 4 + q) ^ (cb & 7)) * 8;    // (cb+128)&7 == cb&7
        bf[ct][0] = *(const half8*)(Bs + cb * 64 + ph);
        bf[ct][1] = *(const half8*)(Bs + (128 + cb) * 64 + ph);
      }
#pragma unroll
      for (int rt = 0; rt < 4; rt++)
#pragma unroll
        for (int ct = 0; ct < 4; ct++) {
          acc[rt][ct][0] = __builtin_amdgcn_mfma_f32_16x16x32_f16(af[rt], bf[ct][0], acc[rt][ct][0], 0, 0, 0);
          acc[rt][ct][1] = __builtin_amdgcn_mfma_f32_16x16x32_f16(af[rt], bf[ct][1], acc[rt][ct][1], 0, 0, 0);
        }
    }
  }

  long ab = (long)z * CAPP * HDIM;
#pragma unroll
  for (int rt = 0; rt < 4; rt++)
#pragma unroll
    for (int ct = 0; ct < 4; ct++)
#pragma unroll
      for (int r = 0; r < 4; r++) {
        int row = m0 + wm * 64 + rt * 16 + q * 4 + r;   // C/D: row = quad*4+reg
        int col = n0 + wn * 64 + ct * 16 + m16;         //      col = lane&15
        float h1 = acc[rt][ct][0][r], h2 = acc[rt][ct][1][r];
        float s = h2 / (1.f + __expf(-h2));
        act[ab + (long)row * HDIM + col] = (_Float16)(h1 * s);
      }
}

// -------------------- GEMM2: plain fp32 stores into ybuf (no atomics) --------------------
__global__ __launch_bounds__(256, 3) void gemm2_kernel(const _Float16* __restrict__ act,
                                                       const _Float16* __restrict__ w2t,
                                                       const int* __restrict__ counts,
                                                       float* __restrict__ ybuf) {
  int i = blockIdx.x;
  int xcd = i & 7, j = i >> 3;       // 480 blocks, 60/xcd
  int m = j % 5, t2 = j / 5;         // t2<12: k=t2&1, n=t2>>1 (0..5)
  int k = t2 & 1, n = t2 >> 1;
  int e = xcd, z = k * 8 + e;
  int count = counts[z];
  int m0 = m * 128;
  if (m0 >= count) return;
  int n0 = n * 128;

  __shared__ _Float16 As[128 * 64];   // 16 KB
  __shared__ _Float16 Bs[128 * 64];   // 16 KB

  int t = threadIdx.x;
  int lane = t & 63, w = t >> 6;
  int l8 = lane >> 3, u8 = lane & 7;

  const _Float16* ag[4]; _Float16* al[4];
#pragma unroll
  for (int s = 0; s < 4; s++) {
    int row = w * 32 + s * 8 + l8;
    ag[s] = act + ((long)z * CAPP + m0 + row) * HDIM + ((u8 ^ (row & 7)) * 8);
    al[s] = As + row * 64 + u8 * 8;
  }
  const _Float16* bg[4]; _Float16* bl[4];
#pragma unroll
  for (int s = 0; s < 4; s++) {
    int rb = w * 32 + s * 8 + l8;
    bg[s] = w2t + ((long)e * DDIM + n0 + rb) * HDIM + ((u8 ^ (rb & 7)) * 8);
    bl[s] = Bs + rb * 64 + u8 * 8;
  }

  int q = lane >> 4, m16 = lane & 15;
  int wm = w & 1, wn = w >> 1;

  f4 zero4 = {0.f, 0.f, 0.f, 0.f};
  f4 acc[4][4];
#pragma unroll
  for (int rt = 0; rt < 4; rt++)
#pragma unroll
    for (int ct = 0; ct < 4; ct++) acc[rt][ct] = zero4;

  for (int kk = 0; kk < HDIM; kk += 64) {
    __syncthreads();
#pragma unroll
    for (int s = 0; s < 4; s++) { gld16(ag[s], al[s]); ag[s] += 64; }
#pragma unroll
    for (int s = 0; s < 4; s++) { gld16(bg[s], bl[s]); bg[s] += 64; }
    __syncthreads();

#pragma unroll
    for (int c = 0; c < 2; c++) {
      half8 af[4], bf[4];
#pragma unroll
      for (int rt = 0; rt < 4; rt++) {
        int row = wm * 64 + rt * 16 + m16;
        af[rt] = *(const half8*)(As + row * 64 + (((c * 4 + q) ^ (row & 7)) * 8));
      }
#pragma unroll
      for (int ct = 0; ct < 4; ct++) {
        int cb = wn * 64 + ct * 16 + m16;
        bf[ct] = *(const half8*)(Bs + cb * 64 + (((c * 4 + q) ^ (cb & 7)) * 8));
      }
#pragma unroll
      for (int rt = 0; rt < 4; rt++)
#pragma unroll
        for (int ct = 0; ct < 4; ct++)
          acc[rt][ct] = __builtin_amdgcn_mfma_f32_16x16x32_f16(af[rt], bf[ct], acc[rt][ct], 0, 0, 0);
    }
  }

  // plain stores: ybuf[slot][col] = y (padded slots written, never gathered)
#pragma unroll
  for (int rt = 0; rt < 4; rt++)
#pragma unroll
    for (int ct = 0; ct < 4; ct++)
#pragma unroll
      for (int r = 0; r < 4; r++) {
        int lr = wm * 64 + rt * 16 + q * 4 + r;
        int col = n0 + wn * 64 + ct * 16 + m16;
        ybuf[((long)z * CAPP + m0 + lr) * DDIM + col] = acc[rt][ct][r];
      }
}

// -------------------- gather: out[tok] = sum_k w_k * ybuf[slot_k] --------------------
__global__ __launch_bounds__(256) void gather_kernel(const float* __restrict__ ybuf,
                                                     const int* __restrict__ inv,
                                                     const float* __restrict__ wts,
                                                     float* __restrict__ out) {
  int t = threadIdx.x;
  int w = t >> 6, lane = t & 63;
  int tok = blockIdx.x * 4 + w;
  int s0 = inv[tok * 2 + 0], s1 = inv[tok * 2 + 1];
  float w0 = wts[tok * 2 + 0], w1 = wts[tok * 2 + 1];
  float acc[12];
#pragma unroll
  for (int j = 0; j < 12; j++) acc[j] = 0.f;
  int b = lane * 12;
  if (s0 >= 0) {
    const float* y = ybuf + (long)s0 * DDIM + b;
#pragma unroll
    for (int v = 0; v < 3; v++) {
      f4 qv = *(const f4*)(y + v * 4);
#pragma unroll
      for (int j = 0; j < 4; j++) acc[v * 4 + j] += w0 * qv[j];
    }
  }
  if (s1 >= 0) {
    const float* y = ybuf + (long)s1 * DDIM + b;
#pragma unroll
    for (int v = 0; v < 3; v++) {
      f4 qv = *(const f4*)(y + v * 4);
#pragma unroll
      for (int j = 0; j < 4; j++) acc[v * 4 + j] += w1 * qv[j];
    }
  }
  float* o = out + (long)tok * DDIM + b;
#pragma unroll
  for (int v = 0; v < 3; v++) {
    f4 qv;
#pragma unroll
    for (int j = 0; j < 4; j++) qv[j] = acc[v * 4 + j];
    *(f4*)(o + v * 4) = qv;
  }
}

// -------------------- launch --------------------

extern "C" void kernel_launch(void* const* d_in, const int* in_sizes, int n_in,
                              void* d_out, int out_size, void* d_ws, size_t ws_size,
                              hipStream_t stream) {
  const float* x  = (const float*)d_in[0];
  const float* Wg = (const float*)d_in[1];
  const float* W1 = (const float*)d_in[2];
  const float* W2 = (const float*)d_in[3];
  float* out = (float*)d_out;
  char* ws = (char*)d_ws;

  _Float16* xh   = (_Float16*)(ws + XH_OFF);
  _Float16* w1t  = (_Float16*)(ws + W1T_OFF);
  float*    ybuf = (float*)(ws + YB_OFF);
  _Float16* w2t  = (_Float16*)(ws + W2T_OFF);
  _Float16* actb = (_Float16*)(ws + ACT_OFF);
  int* eidx      = (int*)(ws + EIDX_OFF);
  float* wts     = (float*)(ws + WTS_OFF);
  int* toklist   = (int*)(ws + TOKL_OFF);
  int* counts    = (int*)(ws + CNT_OFF);
  int* inv       = (int*)(ws + INV_OFF);

  prep1_kernel<<<4097, 256, 0, stream>>>(W1, x, Wg, w1t, xh, eidx, wts);
  scan_kernel<<<16, 64, 0, stream>>>(eidx, toklist, counts, inv);
  gemm1_kernel<<<2816, 256, 0, stream>>>(xh, w1t, W2, w2t, toklist, counts, actb);
  gemm2_kernel<<<480, 256, 0, stream>>>(actb, w2t, counts, ybuf);
  gather_kernel<<<1024, 256, 0, stream>>>(ybuf, inv, wts, out);
}